// Round 16
// baseline (80.025 us; speedup 1.0000x reference)
//
#include <hip/hip_runtime.h>
#include <math.h>

#define NCONST 100
#define NF     16
#define BLK    1024
#define NWAVES 16

typedef _Float16 f16;
typedef _Float16 f16x8 __attribute__((ext_vector_type(8)));
typedef _Float16 f16x4 __attribute__((ext_vector_type(4)));
typedef float    f32x16 __attribute__((ext_vector_type(16)));

// One block per batch element, 1024 threads (16 waves), 2 blocks/CU -> 32
// waves/CU (100% wave capacity). R15 analysis: edge is ~75% dependency-stall
// even in the amplified probe; at 40% occupancy only ~3.2 waves/SIMD hide
// latency. Lean (R12+) structure has ~half the DS traffic of R7's 1024-thread
// attempt, so occupancy is retestable as a lever. Single-variable change vs
// R15: BLK 512->1024, edge stride 8->16. All phase math identical
// (HW-verified R9/R12/R13/R15).
__global__ __launch_bounds__(BLK, 2) void convint_fused(
    const float* __restrict__ x,
    const float* __restrict__ bn_g, const float* __restrict__ bn_b,
    const float* __restrict__ bn_m, const float* __restrict__ bn_v,
    const float* __restrict__ frw1, const float* __restrict__ frb1,
    const float* __restrict__ frw2, const float* __restrict__ frb2,
    const float* __restrict__ frw3, const float* __restrict__ frb3,
    const float* __restrict__ fow1, const float* __restrict__ fob1,
    const float* __restrict__ fow2, const float* __restrict__ fob2,
    const float* __restrict__ fow3, const float* __restrict__ fob3,
    const float* __restrict__ fcw1, const float* __restrict__ fcb1,
    const float* __restrict__ fcw2, const float* __restrict__ fcb2,
    float* __restrict__ out)
{
    __shared__ float xbn[NCONST][NF];    // 6.4 KB
    __shared__ float upool[4000];        // 16 KB: Pr/Ps f16 (edge phase only)
    __shared__ float aggF[NCONST * 8];   // 3.2 KB
    __shared__ float fcin[8];
    __shared__ float hfc[48];
    __shared__ float logits[8];

    char* const PrB = (char*)upool;      // 8000 B, swizzled 16B slots
    char* const PsB = PrB + 8000;        // 8000 B

    const int b   = blockIdx.x;
    const int tid = threadIdx.x;
    const float* xb = x + (size_t)b * (NCONST * NF);

    for (int idx = tid; idx < NCONST * NF; idx += BLK) {
        int f = idx & 15;
        float sc = rsqrtf(bn_v[f] + 1e-3f) * bn_g[f];
        xbn[idx >> 4][f] = (xb[idx] - bn_m[f]) * sc + bn_b[f];
    }
    if (tid < 8) fcin[tid] = 0.f;
    __syncthreads();

    // ---- proj (R9-verified): Pr/Ps f16 rows of 40 halves, swizzled ----
    for (int idx = tid; idx < 1600; idx += BLK) {
        int n   = idx >> 4;
        int rem = idx & 15;
        int sel = rem >> 3;
        int oq  = rem & 7;
        int o0  = oq * 4;
        float xs[16];
        {
            const float4* xv = (const float4*)(&xbn[n][0]);
            float4 x0 = xv[0], x1 = xv[1], x2 = xv[2], x3 = xv[3];
            xs[0]=x0.x; xs[1]=x0.y; xs[2]=x0.z; xs[3]=x0.w;
            xs[4]=x1.x; xs[5]=x1.y; xs[6]=x1.z; xs[7]=x1.w;
            xs[8]=x2.x; xs[9]=x2.y; xs[10]=x2.z; xs[11]=x2.w;
            xs[12]=x3.x; xs[13]=x3.y; xs[14]=x3.z; xs[15]=x3.w;
        }
        float acc0 = (!sel) ? frb1[o0 + 0] : 0.f;
        float acc1 = (!sel) ? frb1[o0 + 1] : 0.f;
        float acc2 = (!sel && oq < 7) ? frb1[o0 + 2] : 0.f;
        float acc3 = (!sel && oq < 7) ? frb1[o0 + 3] : 0.f;
        const float* wbase = frw1 + sel * 16 * 30;
        const int wcol2 = (oq < 7) ? o0 + 2 : 28;
        #pragma unroll
        for (int f = 0; f < 16; ++f) {
            const float* wr = wbase + f * 30;
            float2 wa = *(const float2*)(wr + o0);
            float2 wb = *(const float2*)(wr + wcol2);
            acc0 = fmaf(xs[f], wa.x, acc0);
            acc1 = fmaf(xs[f], wa.y, acc1);
            acc2 = fmaf(xs[f], wb.x, acc2);
            acc3 = fmaf(xs[f], wb.y, acc3);
        }
        f16x4 hv;
        hv[0] = (f16)acc0;
        hv[1] = (f16)acc1;
        hv[2] = (oq < 7) ? (f16)acc2 : (sel ? (f16)0.f : (f16)1.f);  // half30: bias carrier
        hv[3] = (oq < 7) ? (f16)acc3 : (f16)0.f;                     // half31: 0 (k-pad)
        int slot = oq >> 1;
        int sw = (slot & 2) | ((slot ^ (n >> 3)) & 1);
        *(f16x4*)((sel ? PsB : PrB) + n * 80 + sw * 16 + (oq & 1) * 8) = hv;
    }
    __syncthreads();

    // ---- edge phase (R13-verified core, ILP-2, 16 waves) ----
    {
        const int l  = tid & 63;
        const int wv = tid >> 6;      // wave 0..15
        const int e  = l & 31;
        const int hi = l >> 5;

        const int o2p = (e >= 4 && e < 12) ? (e ^ 12) : e;
        const bool o2v = (o2p < 15);
        const int  o2c = o2v ? o2p : 0;
        const bool o3v = (e < 6);
        const int  o3c = o3v ? e : 0;

        f16x8 bf1a, bf1b, bf2p;
        #pragma unroll
        for (int m = 0; m < 8; ++m) {
            int ka  = hi * 8 + m;
            int kb_ = 16 + ka;
            bf1a[m] = o2v ? (f16)frw2[ka * 15 + o2c] : (f16)0.f;
            f16 wb = (f16)0.f;
            if (o2v) {
                if (kb_ < 30)       wb = (f16)frw2[kb_ * 15 + o2c];
                else if (kb_ == 30) wb = (f16)frb2[o2c];
            }
            bf1b[m] = wb;
            f16 w3 = (f16)0.f;
            if (o3v) {
                if (ka < 15)       w3 = (f16)frw3[ka * 6 + o3c];
                else               w3 = (f16)frb3[o3c];
            }
            bf2p[m] = w3;
        }
        f32x16 cz;
        #pragma unroll
        for (int r = 0; r < 16; ++r) cz[r] = 0.f;
        const float gtail = (e < 3) ? 1.f : 0.f;

        for (int base = wv; base < 50; base += NWAVES) {
            const int iA = base, iB = base + 50;
            const char* prpA = PrB + iA * 80 + ((hi ^ ((iA >> 3) & 1)) * 16);
            const char* prpB = PrB + iB * 80 + ((hi ^ ((iB >> 3) & 1)) * 16);
            f16x8 praA = *(const f16x8*)prpA;
            f16x8 prbA = *(const f16x8*)(prpA + 32);
            f16x8 praB = *(const f16x8*)prpB;
            f16x8 prbB = *(const f16x8*)(prpB + 32);
            float a0 = 0.f, a1 = 0.f, a2r = 0.f, a3 = 0.f;
            float b0 = 0.f, b1 = 0.f, b2r = 0.f, b3 = 0.f;

            int jA = iA + 1 + e; if (jA >= 100) jA -= 100;
            int jB = iB + 1 + e; if (jB >= 100) jB -= 100;
            #pragma unroll
            for (int tb = 0; tb < 4; ++tb) {
                const char* pspA = PsB + jA * 80 + ((hi ^ ((jA >> 3) & 1)) * 16);
                const char* pspB = PsB + jB * 80 + ((hi ^ ((jB >> 3) & 1)) * 16);
                f16x8 psaA = *(const f16x8*)pspA;
                f16x8 psbA = *(const f16x8*)(pspA + 32);
                f16x8 psaB = *(const f16x8*)pspB;
                f16x8 psbB = *(const f16x8*)(pspB + 32);

                f16x8 h1aA = praA + psaA, h1bA = prbA + psbA;
                f16x8 h1aB = praB + psaB, h1bB = prbB + psbB;
                #pragma unroll
                for (int m = 0; m < 8; ++m) {
                    h1aA[m] = (h1aA[m] > (f16)0.f) ? h1aA[m] : (f16)0.f;
                    h1bA[m] = (h1bA[m] > (f16)0.f) ? h1bA[m] : (f16)0.f;
                    h1aB[m] = (h1aB[m] > (f16)0.f) ? h1aB[m] : (f16)0.f;
                    h1bB[m] = (h1bB[m] > (f16)0.f) ? h1bB[m] : (f16)0.f;
                }
                f32x16 c1A = __builtin_amdgcn_mfma_f32_32x32x16_f16(bf1a, h1aA, cz, 0, 0, 0);
                f32x16 c1B = __builtin_amdgcn_mfma_f32_32x32x16_f16(bf1a, h1aB, cz, 0, 0, 0);
                c1A = __builtin_amdgcn_mfma_f32_32x32x16_f16(bf1b, h1bA, c1A, 0, 0, 0);
                c1B = __builtin_amdgcn_mfma_f32_32x32x16_f16(bf1b, h1bB, c1B, 0, 0, 0);

                union { int w[4]; f16x8 v; } aA, aB;
                aA.w[0] = __builtin_bit_cast(int, __builtin_amdgcn_cvt_pkrtz(c1A[0], c1A[1]));
                aA.w[1] = __builtin_bit_cast(int, __builtin_amdgcn_cvt_pkrtz(c1A[2], c1A[3]));
                aA.w[2] = __builtin_bit_cast(int, __builtin_amdgcn_cvt_pkrtz(c1A[4], c1A[5]));
                aA.w[3] = __builtin_bit_cast(int, __builtin_amdgcn_cvt_pkrtz(c1A[6], c1A[7]));
                aB.w[0] = __builtin_bit_cast(int, __builtin_amdgcn_cvt_pkrtz(c1B[0], c1B[1]));
                aB.w[1] = __builtin_bit_cast(int, __builtin_amdgcn_cvt_pkrtz(c1B[2], c1B[3]));
                aB.w[2] = __builtin_bit_cast(int, __builtin_amdgcn_cvt_pkrtz(c1B[4], c1B[5]));
                aB.w[3] = __builtin_bit_cast(int, __builtin_amdgcn_cvt_pkrtz(c1B[6], c1B[7]));
                #pragma unroll
                for (int m = 0; m < 8; ++m) {
                    aA.v[m] = (aA.v[m] > (f16)0.f) ? aA.v[m] : (f16)0.f;
                    aB.v[m] = (aB.v[m] > (f16)0.f) ? aB.v[m] : (f16)0.f;
                }
                aA.v[7] = hi ? (f16)1.f : aA.v[7];
                aB.v[7] = hi ? (f16)1.f : aB.v[7];

                f32x16 c2A = __builtin_amdgcn_mfma_f32_32x32x16_f16(bf2p, aA.v, cz, 0, 0, 0);
                f32x16 c2B = __builtin_amdgcn_mfma_f32_32x32x16_f16(bf2p, aB.v, cz, 0, 0, 0);

                if (tb < 3) {
                    a0 += fmaxf(c2A[0], 0.f);  a1 += fmaxf(c2A[1], 0.f);
                    a2r += fmaxf(c2A[2], 0.f); a3 += fmaxf(c2A[3], 0.f);
                    b0 += fmaxf(c2B[0], 0.f);  b1 += fmaxf(c2B[1], 0.f);
                    b2r += fmaxf(c2B[2], 0.f); b3 += fmaxf(c2B[3], 0.f);
                } else {
                    a0 = fmaf(gtail, fmaxf(c2A[0], 0.f), a0);
                    a1 = fmaf(gtail, fmaxf(c2A[1], 0.f), a1);
                    a2r = fmaf(gtail, fmaxf(c2A[2], 0.f), a2r);
                    a3 = fmaf(gtail, fmaxf(c2A[3], 0.f), a3);
                    b0 = fmaf(gtail, fmaxf(c2B[0], 0.f), b0);
                    b1 = fmaf(gtail, fmaxf(c2B[1], 0.f), b1);
                    b2r = fmaf(gtail, fmaxf(c2B[2], 0.f), b2r);
                    b3 = fmaf(gtail, fmaxf(c2B[3], 0.f), b3);
                }
                jA += 32; if (jA >= 100) jA -= 100;
                jB += 32; if (jB >= 100) jB -= 100;
            }
            #pragma unroll
            for (int mk = 1; mk <= 16; mk <<= 1) {
                a0 += __shfl_xor(a0, mk);  a1 += __shfl_xor(a1, mk);
                a2r += __shfl_xor(a2r, mk); a3 += __shfl_xor(a3, mk);
                b0 += __shfl_xor(b0, mk);  b1 += __shfl_xor(b1, mk);
                b2r += __shfl_xor(b2r, mk); b3 += __shfl_xor(b3, mk);
            }
            if (l == 0) {
                float4 v; v.x = a0; v.y = a1; v.z = a2r; v.w = a3;
                *(float4*)&aggF[iA * 8] = v;
                float4 w; w.x = b0; w.y = b1; w.z = b2r; w.w = b3;
                *(float4*)&aggF[iB * 8] = w;
            } else if (l == 32) {
                float2 v; v.x = a0; v.y = a1;
                *(float2*)&aggF[iA * 8 + 4] = v;
                float2 w; w.x = b0; w.y = b1;
                *(float2*)&aggF[iB * 8 + 4] = w;
            }
        }
    }
    __syncthreads();

    // ---- fo MLP: per-node register chain (R15-verified) ----
    {
        const int wvF = tid >> 6;
        const int lF  = tid & 63;
        if (wvF < 4 && lF < 25) {
            const int n = wvF * 25 + lF;
            float in[22];
            {
                const float4* xv = (const float4*)(&xbn[n][0]);
                float4 q0 = xv[0], q1 = xv[1], q2 = xv[2], q3 = xv[3];
                in[0]=q0.x;  in[1]=q0.y;  in[2]=q0.z;  in[3]=q0.w;
                in[4]=q1.x;  in[5]=q1.y;  in[6]=q1.z;  in[7]=q1.w;
                in[8]=q2.x;  in[9]=q2.y;  in[10]=q2.z; in[11]=q2.w;
                in[12]=q3.x; in[13]=q3.y; in[14]=q3.z; in[15]=q3.w;
                const float4 g0 = *(const float4*)(&aggF[n * 8]);
                const float2 g1 = *(const float2*)(&aggF[n * 8 + 4]);
                in[16]=g0.x; in[17]=g0.y; in[18]=g0.z; in[19]=g0.w;
                in[20]=g1.x; in[21]=g1.y;
            }
            float h1[45];
            #pragma unroll
            for (int o = 0; o < 45; ++o) h1[o] = fob1[o];
            #pragma unroll
            for (int k = 0; k < 22; ++k) {
                float v = in[k];
                #pragma unroll
                for (int o = 0; o < 45; ++o) h1[o] = fmaf(v, fow1[k * 45 + o], h1[o]);
            }
            #pragma unroll
            for (int o = 0; o < 45; ++o) h1[o] = fmaxf(h1[o], 0.f);

            float h2[22];
            #pragma unroll
            for (int o = 0; o < 22; ++o) h2[o] = fob2[o];
            #pragma unroll
            for (int k = 0; k < 45; ++k) {
                float v = h1[k];
                #pragma unroll
                for (int o = 0; o < 22; ++o) h2[o] = fmaf(v, fow2[k * 22 + o], h2[o]);
            }
            #pragma unroll
            for (int o = 0; o < 22; ++o) h2[o] = fmaxf(h2[o], 0.f);

            #pragma unroll
            for (int c = 0; c < 6; ++c) {
                float acc = fob3[c];
                #pragma unroll
                for (int k = 0; k < 22; ++k) acc = fmaf(h2[k], fow3[k * 6 + c], acc);
                atomicAdd(&fcin[c], fmaxf(acc, 0.f));
            }
        }
    }
    __syncthreads();

    // ---- fc: 6 -> 48 (relu) -> 5 -> softmax ----
    if (tid < 48) {
        float acc = fcb1[tid];
        #pragma unroll
        for (int k = 0; k < 6; ++k) acc = fmaf(fcin[k], fcw1[k * 48 + tid], acc);
        hfc[tid] = fmaxf(acc, 0.f);
    }
    __syncthreads();
    if (tid < 5) {
        float acc = fcb2[tid];
        #pragma unroll
        for (int k = 0; k < 48; ++k) acc = fmaf(hfc[k], fcw2[k * 5 + tid], acc);
        logits[tid] = acc;
    }
    __syncthreads();
    if (tid == 0) {
        float m = logits[0];
        #pragma unroll
        for (int c = 1; c < 5; ++c) m = fmaxf(m, logits[c]);
        float ex[5], sum = 0.f;
        #pragma unroll
        for (int c = 0; c < 5; ++c) { ex[c] = __expf(logits[c] - m); sum += ex[c]; }
        float inv = 1.f / sum;
        #pragma unroll
        for (int c = 0; c < 5; ++c) out[(size_t)b * 5 + c] = ex[c] * inv;
    }
}

extern "C" void kernel_launch(void* const* d_in, const int* in_sizes, int n_in,
                              void* d_out, int out_size, void* d_ws, size_t ws_size,
                              hipStream_t stream) {
    const float* x     = (const float*)d_in[0];
    const float* bn_g  = (const float*)d_in[1];
    const float* bn_b  = (const float*)d_in[2];
    const float* bn_m  = (const float*)d_in[3];
    const float* bn_v  = (const float*)d_in[4];
    const float* frw1  = (const float*)d_in[5];
    const float* frb1  = (const float*)d_in[6];
    const float* frw2  = (const float*)d_in[7];
    const float* frb2  = (const float*)d_in[8];
    const float* frw3  = (const float*)d_in[9];
    const float* frb3  = (const float*)d_in[10];
    const float* fow1  = (const float*)d_in[11];
    const float* fob1  = (const float*)d_in[12];
    const float* fow2  = (const float*)d_in[13];
    const float* fob2  = (const float*)d_in[14];
    const float* fow3  = (const float*)d_in[15];
    const float* fob3  = (const float*)d_in[16];
    const float* fcw1  = (const float*)d_in[17];
    const float* fcb1  = (const float*)d_in[18];
    const float* fcw2  = (const float*)d_in[19];
    const float* fcb2  = (const float*)d_in[20];

    const int B = in_sizes[0] / (NCONST * NF);   // 512

    convint_fused<<<dim3(B), dim3(BLK), 0, stream>>>(
        x, bn_g, bn_b, bn_m, bn_v,
        frw1, frb1, frw2, frb2, frw3, frb3,
        fow1, fob1, fow2, fob2, fow3, fob3,
        fcw1, fcb1, fcw2, fcb2,
        (float*)d_out);
}

// Round 17
// 65.551 us; speedup vs baseline: 1.2208x; 1.2208x over previous
//
#include <hip/hip_runtime.h>
#include <math.h>

#define NCONST 100
#define NF     16
#define BLK    512

typedef _Float16 f16;
typedef _Float16 f16x8 __attribute__((ext_vector_type(8)));
typedef _Float16 f16x4 __attribute__((ext_vector_type(4)));
typedef float    f32x16 __attribute__((ext_vector_type(16)));

// One block per batch element, 512 threads (8 waves). R15 base (best 60.6us)
// with two latency cuts:
//  (1) edge: MFMA1a/1b now use INDEPENDENT accumulators (summed at pack on
//      the 8 used regs) -- removes the serial C-chain MFMA->MFMA stage.
//      b2 still rides k=30 inside the c1b term; math identical.
//  (2) fo: nodes spread 8 waves x 13 lanes (was 4x25) -> 2 waves/SIMD to
//      hide the s_load weight stream.
// R16 lesson: 1024-thread blocks regress (wave imbalance + barrier cost);
// occupancy is a dead lever for this kernel (falsified 3x).
__global__ __launch_bounds__(BLK, 4) void convint_fused(
    const float* __restrict__ x,
    const float* __restrict__ bn_g, const float* __restrict__ bn_b,
    const float* __restrict__ bn_m, const float* __restrict__ bn_v,
    const float* __restrict__ frw1, const float* __restrict__ frb1,
    const float* __restrict__ frw2, const float* __restrict__ frb2,
    const float* __restrict__ frw3, const float* __restrict__ frb3,
    const float* __restrict__ fow1, const float* __restrict__ fob1,
    const float* __restrict__ fow2, const float* __restrict__ fob2,
    const float* __restrict__ fow3, const float* __restrict__ fob3,
    const float* __restrict__ fcw1, const float* __restrict__ fcb1,
    const float* __restrict__ fcw2, const float* __restrict__ fcb2,
    float* __restrict__ out)
{
    __shared__ float xbn[NCONST][NF];    // 6.4 KB
    __shared__ float upool[4000];        // 16 KB: Pr/Ps f16 (edge phase only)
    __shared__ float aggF[NCONST * 8];   // 3.2 KB
    __shared__ float fcin[8];
    __shared__ float hfc[48];
    __shared__ float logits[8];

    char* const PrB = (char*)upool;      // 8000 B, swizzled 16B slots
    char* const PsB = PrB + 8000;        // 8000 B

    const int b   = blockIdx.x;
    const int tid = threadIdx.x;
    const float* xb = x + (size_t)b * (NCONST * NF);

    for (int idx = tid; idx < NCONST * NF; idx += BLK) {
        int f = idx & 15;
        float sc = rsqrtf(bn_v[f] + 1e-3f) * bn_g[f];
        xbn[idx >> 4][f] = (xb[idx] - bn_m[f]) * sc + bn_b[f];
    }
    if (tid < 8) fcin[tid] = 0.f;
    __syncthreads();

    // ---- proj (R9-verified): Pr/Ps f16 rows of 40 halves, swizzled ----
    for (int idx = tid; idx < 1600; idx += BLK) {
        int n   = idx >> 4;
        int rem = idx & 15;
        int sel = rem >> 3;
        int oq  = rem & 7;
        int o0  = oq * 4;
        float xs[16];
        {
            const float4* xv = (const float4*)(&xbn[n][0]);
            float4 x0 = xv[0], x1 = xv[1], x2 = xv[2], x3 = xv[3];
            xs[0]=x0.x; xs[1]=x0.y; xs[2]=x0.z; xs[3]=x0.w;
            xs[4]=x1.x; xs[5]=x1.y; xs[6]=x1.z; xs[7]=x1.w;
            xs[8]=x2.x; xs[9]=x2.y; xs[10]=x2.z; xs[11]=x2.w;
            xs[12]=x3.x; xs[13]=x3.y; xs[14]=x3.z; xs[15]=x3.w;
        }
        float acc0 = (!sel) ? frb1[o0 + 0] : 0.f;
        float acc1 = (!sel) ? frb1[o0 + 1] : 0.f;
        float acc2 = (!sel && oq < 7) ? frb1[o0 + 2] : 0.f;
        float acc3 = (!sel && oq < 7) ? frb1[o0 + 3] : 0.f;
        const float* wbase = frw1 + sel * 16 * 30;
        const int wcol2 = (oq < 7) ? o0 + 2 : 28;
        #pragma unroll
        for (int f = 0; f < 16; ++f) {
            const float* wr = wbase + f * 30;
            float2 wa = *(const float2*)(wr + o0);
            float2 wb = *(const float2*)(wr + wcol2);
            acc0 = fmaf(xs[f], wa.x, acc0);
            acc1 = fmaf(xs[f], wa.y, acc1);
            acc2 = fmaf(xs[f], wb.x, acc2);
            acc3 = fmaf(xs[f], wb.y, acc3);
        }
        f16x4 hv;
        hv[0] = (f16)acc0;
        hv[1] = (f16)acc1;
        hv[2] = (oq < 7) ? (f16)acc2 : (sel ? (f16)0.f : (f16)1.f);  // half30: bias carrier
        hv[3] = (oq < 7) ? (f16)acc3 : (f16)0.f;                     // half31: 0 (k-pad)
        int slot = oq >> 1;
        int sw = (slot & 2) | ((slot ^ (n >> 3)) & 1);
        *(f16x4*)((sel ? PsB : PrB) + n * 80 + sw * 16 + (oq & 1) * 8) = hv;
    }
    __syncthreads();

    // ---- edge phase (R13 core, ILP-2, split MFMA1 accumulators) ----
    {
        const int l  = tid & 63;
        const int wv = tid >> 6;
        const int e  = l & 31;
        const int hi = l >> 5;

        const int o2p = (e >= 4 && e < 12) ? (e ^ 12) : e;
        const bool o2v = (o2p < 15);
        const int  o2c = o2v ? o2p : 0;
        const bool o3v = (e < 6);
        const int  o3c = o3v ? e : 0;

        f16x8 bf1a, bf1b, bf2p;
        #pragma unroll
        for (int m = 0; m < 8; ++m) {
            int ka  = hi * 8 + m;
            int kb_ = 16 + ka;
            bf1a[m] = o2v ? (f16)frw2[ka * 15 + o2c] : (f16)0.f;
            f16 wb = (f16)0.f;
            if (o2v) {
                if (kb_ < 30)       wb = (f16)frw2[kb_ * 15 + o2c];
                else if (kb_ == 30) wb = (f16)frb2[o2c];
            }
            bf1b[m] = wb;
            f16 w3 = (f16)0.f;
            if (o3v) {
                if (ka < 15)       w3 = (f16)frw3[ka * 6 + o3c];
                else               w3 = (f16)frb3[o3c];
            }
            bf2p[m] = w3;
        }
        f32x16 cz;
        #pragma unroll
        for (int r = 0; r < 16; ++r) cz[r] = 0.f;
        const float gtail = (e < 3) ? 1.f : 0.f;

        for (int base = wv; base < 50; base += 8) {
            const int iA = base, iB = base + 50;
            const char* prpA = PrB + iA * 80 + ((hi ^ ((iA >> 3) & 1)) * 16);
            const char* prpB = PrB + iB * 80 + ((hi ^ ((iB >> 3) & 1)) * 16);
            f16x8 praA = *(const f16x8*)prpA;
            f16x8 prbA = *(const f16x8*)(prpA + 32);
            f16x8 praB = *(const f16x8*)prpB;
            f16x8 prbB = *(const f16x8*)(prpB + 32);
            float a0 = 0.f, a1 = 0.f, a2r = 0.f, a3 = 0.f;
            float b0 = 0.f, b1 = 0.f, b2r = 0.f, b3 = 0.f;

            int jA = iA + 1 + e; if (jA >= 100) jA -= 100;
            int jB = iB + 1 + e; if (jB >= 100) jB -= 100;
            #pragma unroll
            for (int tb = 0; tb < 4; ++tb) {
                const char* pspA = PsB + jA * 80 + ((hi ^ ((jA >> 3) & 1)) * 16);
                const char* pspB = PsB + jB * 80 + ((hi ^ ((jB >> 3) & 1)) * 16);
                f16x8 psaA = *(const f16x8*)pspA;
                f16x8 psbA = *(const f16x8*)(pspA + 32);
                f16x8 psaB = *(const f16x8*)pspB;
                f16x8 psbB = *(const f16x8*)(pspB + 32);

                f16x8 h1aA = praA + psaA, h1bA = prbA + psbA;
                f16x8 h1aB = praB + psaB, h1bB = prbB + psbB;
                #pragma unroll
                for (int m = 0; m < 8; ++m) {
                    h1aA[m] = (h1aA[m] > (f16)0.f) ? h1aA[m] : (f16)0.f;
                    h1bA[m] = (h1bA[m] > (f16)0.f) ? h1bA[m] : (f16)0.f;
                    h1aB[m] = (h1aB[m] > (f16)0.f) ? h1aB[m] : (f16)0.f;
                    h1bB[m] = (h1bB[m] > (f16)0.f) ? h1bB[m] : (f16)0.f;
                }
                // Four INDEPENDENT MFMAs (no C-chain); sum on the 8 used regs.
                f32x16 c1A  = __builtin_amdgcn_mfma_f32_32x32x16_f16(bf1a, h1aA, cz, 0, 0, 0);
                f32x16 c1Ab = __builtin_amdgcn_mfma_f32_32x32x16_f16(bf1b, h1bA, cz, 0, 0, 0);
                f32x16 c1B  = __builtin_amdgcn_mfma_f32_32x32x16_f16(bf1a, h1aB, cz, 0, 0, 0);
                f32x16 c1Bb = __builtin_amdgcn_mfma_f32_32x32x16_f16(bf1b, h1bB, cz, 0, 0, 0);

                union { int w[4]; f16x8 v; } aA, aB;
                aA.w[0] = __builtin_bit_cast(int, __builtin_amdgcn_cvt_pkrtz(c1A[0] + c1Ab[0], c1A[1] + c1Ab[1]));
                aA.w[1] = __builtin_bit_cast(int, __builtin_amdgcn_cvt_pkrtz(c1A[2] + c1Ab[2], c1A[3] + c1Ab[3]));
                aA.w[2] = __builtin_bit_cast(int, __builtin_amdgcn_cvt_pkrtz(c1A[4] + c1Ab[4], c1A[5] + c1Ab[5]));
                aA.w[3] = __builtin_bit_cast(int, __builtin_amdgcn_cvt_pkrtz(c1A[6] + c1Ab[6], c1A[7] + c1Ab[7]));
                aB.w[0] = __builtin_bit_cast(int, __builtin_amdgcn_cvt_pkrtz(c1B[0] + c1Bb[0], c1B[1] + c1Bb[1]));
                aB.w[1] = __builtin_bit_cast(int, __builtin_amdgcn_cvt_pkrtz(c1B[2] + c1Bb[2], c1B[3] + c1Bb[3]));
                aB.w[2] = __builtin_bit_cast(int, __builtin_amdgcn_cvt_pkrtz(c1B[4] + c1Bb[4], c1B[5] + c1Bb[5]));
                aB.w[3] = __builtin_bit_cast(int, __builtin_amdgcn_cvt_pkrtz(c1B[6] + c1Bb[6], c1B[7] + c1Bb[7]));
                #pragma unroll
                for (int m = 0; m < 8; ++m) {
                    aA.v[m] = (aA.v[m] > (f16)0.f) ? aA.v[m] : (f16)0.f;
                    aB.v[m] = (aB.v[m] > (f16)0.f) ? aB.v[m] : (f16)0.f;
                }
                aA.v[7] = hi ? (f16)1.f : aA.v[7];   // k2=15 bias slot
                aB.v[7] = hi ? (f16)1.f : aB.v[7];

                f32x16 c2A = __builtin_amdgcn_mfma_f32_32x32x16_f16(bf2p, aA.v, cz, 0, 0, 0);
                f32x16 c2B = __builtin_amdgcn_mfma_f32_32x32x16_f16(bf2p, aB.v, cz, 0, 0, 0);

                if (tb < 3) {
                    a0 += fmaxf(c2A[0], 0.f);  a1 += fmaxf(c2A[1], 0.f);
                    a2r += fmaxf(c2A[2], 0.f); a3 += fmaxf(c2A[3], 0.f);
                    b0 += fmaxf(c2B[0], 0.f);  b1 += fmaxf(c2B[1], 0.f);
                    b2r += fmaxf(c2B[2], 0.f); b3 += fmaxf(c2B[3], 0.f);
                } else {
                    a0 = fmaf(gtail, fmaxf(c2A[0], 0.f), a0);
                    a1 = fmaf(gtail, fmaxf(c2A[1], 0.f), a1);
                    a2r = fmaf(gtail, fmaxf(c2A[2], 0.f), a2r);
                    a3 = fmaf(gtail, fmaxf(c2A[3], 0.f), a3);
                    b0 = fmaf(gtail, fmaxf(c2B[0], 0.f), b0);
                    b1 = fmaf(gtail, fmaxf(c2B[1], 0.f), b1);
                    b2r = fmaf(gtail, fmaxf(c2B[2], 0.f), b2r);
                    b3 = fmaf(gtail, fmaxf(c2B[3], 0.f), b3);
                }
                jA += 32; if (jA >= 100) jA -= 100;
                jB += 32; if (jB >= 100) jB -= 100;
            }
            #pragma unroll
            for (int mk = 1; mk <= 16; mk <<= 1) {
                a0 += __shfl_xor(a0, mk);  a1 += __shfl_xor(a1, mk);
                a2r += __shfl_xor(a2r, mk); a3 += __shfl_xor(a3, mk);
                b0 += __shfl_xor(b0, mk);  b1 += __shfl_xor(b1, mk);
                b2r += __shfl_xor(b2r, mk); b3 += __shfl_xor(b3, mk);
            }
            if (l == 0) {
                float4 v; v.x = a0; v.y = a1; v.z = a2r; v.w = a3;
                *(float4*)&aggF[iA * 8] = v;
                float4 w; w.x = b0; w.y = b1; w.z = b2r; w.w = b3;
                *(float4*)&aggF[iB * 8] = w;
            } else if (l == 32) {
                float2 v; v.x = a0; v.y = a1;
                *(float2*)&aggF[iA * 8 + 4] = v;
                float2 w; w.x = b0; w.y = b1;
                *(float2*)&aggF[iB * 8 + 4] = w;
            }
        }
    }
    __syncthreads();

    // ---- fo MLP: per-node register chain, 8 waves x 13 lanes ----
    {
        const int wvF = tid >> 6;
        const int lF  = tid & 63;
        const int n   = wvF * 13 + lF;
        if (lF < 13 && n < NCONST) {
            float in[22];
            {
                const float4* xv = (const float4*)(&xbn[n][0]);
                float4 q0 = xv[0], q1 = xv[1], q2 = xv[2], q3 = xv[3];
                in[0]=q0.x;  in[1]=q0.y;  in[2]=q0.z;  in[3]=q0.w;
                in[4]=q1.x;  in[5]=q1.y;  in[6]=q1.z;  in[7]=q1.w;
                in[8]=q2.x;  in[9]=q2.y;  in[10]=q2.z; in[11]=q2.w;
                in[12]=q3.x; in[13]=q3.y; in[14]=q3.z; in[15]=q3.w;
                const float4 g0 = *(const float4*)(&aggF[n * 8]);
                const float2 g1 = *(const float2*)(&aggF[n * 8 + 4]);
                in[16]=g0.x; in[17]=g0.y; in[18]=g0.z; in[19]=g0.w;
                in[20]=g1.x; in[21]=g1.y;
            }
            float h1[45];
            #pragma unroll
            for (int o = 0; o < 45; ++o) h1[o] = fob1[o];
            #pragma unroll
            for (int k = 0; k < 22; ++k) {
                float v = in[k];
                #pragma unroll
                for (int o = 0; o < 45; ++o) h1[o] = fmaf(v, fow1[k * 45 + o], h1[o]);
            }
            #pragma unroll
            for (int o = 0; o < 45; ++o) h1[o] = fmaxf(h1[o], 0.f);

            float h2[22];
            #pragma unroll
            for (int o = 0; o < 22; ++o) h2[o] = fob2[o];
            #pragma unroll
            for (int k = 0; k < 45; ++k) {
                float v = h1[k];
                #pragma unroll
                for (int o = 0; o < 22; ++o) h2[o] = fmaf(v, fow2[k * 22 + o], h2[o]);
            }
            #pragma unroll
            for (int o = 0; o < 22; ++o) h2[o] = fmaxf(h2[o], 0.f);

            #pragma unroll
            for (int c = 0; c < 6; ++c) {
                float acc = fob3[c];
                #pragma unroll
                for (int k = 0; k < 22; ++k) acc = fmaf(h2[k], fow3[k * 6 + c], acc);
                atomicAdd(&fcin[c], fmaxf(acc, 0.f));
            }
        }
    }
    __syncthreads();

    // ---- fc: 6 -> 48 (relu) -> 5 -> softmax ----
    if (tid < 48) {
        float acc = fcb1[tid];
        #pragma unroll
        for (int k = 0; k < 6; ++k) acc = fmaf(fcin[k], fcw1[k * 48 + tid], acc);
        hfc[tid] = fmaxf(acc, 0.f);
    }
    __syncthreads();
    if (tid < 5) {
        float acc = fcb2[tid];
        #pragma unroll
        for (int k = 0; k < 48; ++k) acc = fmaf(hfc[k], fcw2[k * 5 + tid], acc);
        logits[tid] = acc;
    }
    __syncthreads();
    if (tid == 0) {
        float m = logits[0];
        #pragma unroll
        for (int c = 1; c < 5; ++c) m = fmaxf(m, logits[c]);
        float ex[5], sum = 0.f;
        #pragma unroll
        for (int c = 0; c < 5; ++c) { ex[c] = __expf(logits[c] - m); sum += ex[c]; }
        float inv = 1.f / sum;
        #pragma unroll
        for (int c = 0; c < 5; ++c) out[(size_t)b * 5 + c] = ex[c] * inv;
    }
}

extern "C" void kernel_launch(void* const* d_in, const int* in_sizes, int n_in,
                              void* d_out, int out_size, void* d_ws, size_t ws_size,
                              hipStream_t stream) {
    const float* x     = (const float*)d_in[0];
    const float* bn_g  = (const float*)d_in[1];
    const float* bn_b  = (const float*)d_in[2];
    const float* bn_m  = (const float*)d_in[3];
    const float* bn_v  = (const float*)d_in[4];
    const float* frw1  = (const float*)d_in[5];
    const float* frb1  = (const float*)d_in[6];
    const float* frw2  = (const float*)d_in[7];
    const float* frb2  = (const float*)d_in[8];
    const float* frw3  = (const float*)d_in[9];
    const float* frb3  = (const float*)d_in[10];
    const float* fow1  = (const float*)d_in[11];
    const float* fob1  = (const float*)d_in[12];
    const float* fow2  = (const float*)d_in[13];
    const float* fob2  = (const float*)d_in[14];
    const float* fow3  = (const float*)d_in[15];
    const float* fob3  = (const float*)d_in[16];
    const float* fcw1  = (const float*)d_in[17];
    const float* fcb1  = (const float*)d_in[18];
    const float* fcw2  = (const float*)d_in[19];
    const float* fcb2  = (const float*)d_in[20];

    const int B = in_sizes[0] / (NCONST * NF);   // 512

    convint_fused<<<dim3(B), dim3(BLK), 0, stream>>>(
        x, bn_g, bn_b, bn_m, bn_v,
        frw1, frb1, frw2, frb2, frw3, frb3,
        fow1, fob1, fow2, fob2, fow3, fob3,
        fcw1, fcb1, fcw2, fcb2,
        (float*)d_out);
}

// Round 18
// 64.048 us; speedup vs baseline: 1.2495x; 1.0235x over previous
//
#include <hip/hip_runtime.h>
#include <math.h>

#define NCONST 100
#define NF     16
#define BLK    512

typedef _Float16 f16;
typedef _Float16 f16x8 __attribute__((ext_vector_type(8)));
typedef _Float16 f16x4 __attribute__((ext_vector_type(4)));
typedef float    f32x16 __attribute__((ext_vector_type(16)));

// One block per batch element, 512 threads (8 waves). R15 edge core restored
// (C-chained MFMA1 pair -- R17 falsified the split-accumulator variant: +16
// VALU/tile cost more than the removed MFMA chain stage). Single change vs
// R15: fo nodes spread 8 waves x 13 lanes (was 4x25) -> 2 waves/SIMD for the
// s_load-paced fo chain. Occupancy falsified 3x as a lever (R8/R10/R16);
// VALU count is the edge currency (R12/R14/R17).
__global__ __launch_bounds__(BLK, 4) void convint_fused(
    const float* __restrict__ x,
    const float* __restrict__ bn_g, const float* __restrict__ bn_b,
    const float* __restrict__ bn_m, const float* __restrict__ bn_v,
    const float* __restrict__ frw1, const float* __restrict__ frb1,
    const float* __restrict__ frw2, const float* __restrict__ frb2,
    const float* __restrict__ frw3, const float* __restrict__ frb3,
    const float* __restrict__ fow1, const float* __restrict__ fob1,
    const float* __restrict__ fow2, const float* __restrict__ fob2,
    const float* __restrict__ fow3, const float* __restrict__ fob3,
    const float* __restrict__ fcw1, const float* __restrict__ fcb1,
    const float* __restrict__ fcw2, const float* __restrict__ fcb2,
    float* __restrict__ out)
{
    __shared__ float xbn[NCONST][NF];    // 6.4 KB
    __shared__ float upool[4000];        // 16 KB: Pr/Ps f16 (edge phase only)
    __shared__ float aggF[NCONST * 8];   // 3.2 KB
    __shared__ float fcin[8];
    __shared__ float hfc[48];
    __shared__ float logits[8];

    char* const PrB = (char*)upool;      // 8000 B, swizzled 16B slots
    char* const PsB = PrB + 8000;        // 8000 B

    const int b   = blockIdx.x;
    const int tid = threadIdx.x;
    const float* xb = x + (size_t)b * (NCONST * NF);

    for (int idx = tid; idx < NCONST * NF; idx += BLK) {
        int f = idx & 15;
        float sc = rsqrtf(bn_v[f] + 1e-3f) * bn_g[f];
        xbn[idx >> 4][f] = (xb[idx] - bn_m[f]) * sc + bn_b[f];
    }
    if (tid < 8) fcin[tid] = 0.f;
    __syncthreads();

    // ---- proj (R9-verified): Pr/Ps f16 rows of 40 halves, swizzled ----
    for (int idx = tid; idx < 1600; idx += BLK) {
        int n   = idx >> 4;
        int rem = idx & 15;
        int sel = rem >> 3;
        int oq  = rem & 7;
        int o0  = oq * 4;
        float xs[16];
        {
            const float4* xv = (const float4*)(&xbn[n][0]);
            float4 x0 = xv[0], x1 = xv[1], x2 = xv[2], x3 = xv[3];
            xs[0]=x0.x; xs[1]=x0.y; xs[2]=x0.z; xs[3]=x0.w;
            xs[4]=x1.x; xs[5]=x1.y; xs[6]=x1.z; xs[7]=x1.w;
            xs[8]=x2.x; xs[9]=x2.y; xs[10]=x2.z; xs[11]=x2.w;
            xs[12]=x3.x; xs[13]=x3.y; xs[14]=x3.z; xs[15]=x3.w;
        }
        float acc0 = (!sel) ? frb1[o0 + 0] : 0.f;
        float acc1 = (!sel) ? frb1[o0 + 1] : 0.f;
        float acc2 = (!sel && oq < 7) ? frb1[o0 + 2] : 0.f;
        float acc3 = (!sel && oq < 7) ? frb1[o0 + 3] : 0.f;
        const float* wbase = frw1 + sel * 16 * 30;
        const int wcol2 = (oq < 7) ? o0 + 2 : 28;
        #pragma unroll
        for (int f = 0; f < 16; ++f) {
            const float* wr = wbase + f * 30;
            float2 wa = *(const float2*)(wr + o0);
            float2 wb = *(const float2*)(wr + wcol2);
            acc0 = fmaf(xs[f], wa.x, acc0);
            acc1 = fmaf(xs[f], wa.y, acc1);
            acc2 = fmaf(xs[f], wb.x, acc2);
            acc3 = fmaf(xs[f], wb.y, acc3);
        }
        f16x4 hv;
        hv[0] = (f16)acc0;
        hv[1] = (f16)acc1;
        hv[2] = (oq < 7) ? (f16)acc2 : (sel ? (f16)0.f : (f16)1.f);  // half30: bias carrier
        hv[3] = (oq < 7) ? (f16)acc3 : (f16)0.f;                     // half31: 0 (k-pad)
        int slot = oq >> 1;
        int sw = (slot & 2) | ((slot ^ (n >> 3)) & 1);
        *(f16x4*)((sel ? PsB : PrB) + n * 80 + sw * 16 + (oq & 1) * 8) = hv;
    }
    __syncthreads();

    // ---- edge phase (R13/R15-verified core, ILP-2, C-chained MFMA1) ----
    {
        const int l  = tid & 63;
        const int wv = tid >> 6;
        const int e  = l & 31;
        const int hi = l >> 5;

        const int o2p = (e >= 4 && e < 12) ? (e ^ 12) : e;
        const bool o2v = (o2p < 15);
        const int  o2c = o2v ? o2p : 0;
        const bool o3v = (e < 6);
        const int  o3c = o3v ? e : 0;

        f16x8 bf1a, bf1b, bf2p;
        #pragma unroll
        for (int m = 0; m < 8; ++m) {
            int ka  = hi * 8 + m;
            int kb_ = 16 + ka;
            bf1a[m] = o2v ? (f16)frw2[ka * 15 + o2c] : (f16)0.f;
            f16 wb = (f16)0.f;
            if (o2v) {
                if (kb_ < 30)       wb = (f16)frw2[kb_ * 15 + o2c];
                else if (kb_ == 30) wb = (f16)frb2[o2c];
            }
            bf1b[m] = wb;
            f16 w3 = (f16)0.f;
            if (o3v) {
                if (ka < 15)       w3 = (f16)frw3[ka * 6 + o3c];
                else               w3 = (f16)frb3[o3c];
            }
            bf2p[m] = w3;
        }
        f32x16 cz;
        #pragma unroll
        for (int r = 0; r < 16; ++r) cz[r] = 0.f;
        const float gtail = (e < 3) ? 1.f : 0.f;

        for (int base = wv; base < 50; base += 8) {
            const int iA = base, iB = base + 50;
            const char* prpA = PrB + iA * 80 + ((hi ^ ((iA >> 3) & 1)) * 16);
            const char* prpB = PrB + iB * 80 + ((hi ^ ((iB >> 3) & 1)) * 16);
            f16x8 praA = *(const f16x8*)prpA;
            f16x8 prbA = *(const f16x8*)(prpA + 32);
            f16x8 praB = *(const f16x8*)prpB;
            f16x8 prbB = *(const f16x8*)(prpB + 32);
            float a0 = 0.f, a1 = 0.f, a2r = 0.f, a3 = 0.f;
            float b0 = 0.f, b1 = 0.f, b2r = 0.f, b3 = 0.f;

            int jA = iA + 1 + e; if (jA >= 100) jA -= 100;
            int jB = iB + 1 + e; if (jB >= 100) jB -= 100;
            #pragma unroll
            for (int tb = 0; tb < 4; ++tb) {
                const char* pspA = PsB + jA * 80 + ((hi ^ ((jA >> 3) & 1)) * 16);
                const char* pspB = PsB + jB * 80 + ((hi ^ ((jB >> 3) & 1)) * 16);
                f16x8 psaA = *(const f16x8*)pspA;
                f16x8 psbA = *(const f16x8*)(pspA + 32);
                f16x8 psaB = *(const f16x8*)pspB;
                f16x8 psbB = *(const f16x8*)(pspB + 32);

                f16x8 h1aA = praA + psaA, h1bA = prbA + psbA;
                f16x8 h1aB = praB + psaB, h1bB = prbB + psbB;
                #pragma unroll
                for (int m = 0; m < 8; ++m) {
                    h1aA[m] = (h1aA[m] > (f16)0.f) ? h1aA[m] : (f16)0.f;
                    h1bA[m] = (h1bA[m] > (f16)0.f) ? h1bA[m] : (f16)0.f;
                    h1aB[m] = (h1aB[m] > (f16)0.f) ? h1aB[m] : (f16)0.f;
                    h1bB[m] = (h1bB[m] > (f16)0.f) ? h1bB[m] : (f16)0.f;
                }
                f32x16 c1A = __builtin_amdgcn_mfma_f32_32x32x16_f16(bf1a, h1aA, cz, 0, 0, 0);
                f32x16 c1B = __builtin_amdgcn_mfma_f32_32x32x16_f16(bf1a, h1aB, cz, 0, 0, 0);
                c1A = __builtin_amdgcn_mfma_f32_32x32x16_f16(bf1b, h1bA, c1A, 0, 0, 0);
                c1B = __builtin_amdgcn_mfma_f32_32x32x16_f16(bf1b, h1bB, c1B, 0, 0, 0);

                union { int w[4]; f16x8 v; } aA, aB;
                aA.w[0] = __builtin_bit_cast(int, __builtin_amdgcn_cvt_pkrtz(c1A[0], c1A[1]));
                aA.w[1] = __builtin_bit_cast(int, __builtin_amdgcn_cvt_pkrtz(c1A[2], c1A[3]));
                aA.w[2] = __builtin_bit_cast(int, __builtin_amdgcn_cvt_pkrtz(c1A[4], c1A[5]));
                aA.w[3] = __builtin_bit_cast(int, __builtin_amdgcn_cvt_pkrtz(c1A[6], c1A[7]));
                aB.w[0] = __builtin_bit_cast(int, __builtin_amdgcn_cvt_pkrtz(c1B[0], c1B[1]));
                aB.w[1] = __builtin_bit_cast(int, __builtin_amdgcn_cvt_pkrtz(c1B[2], c1B[3]));
                aB.w[2] = __builtin_bit_cast(int, __builtin_amdgcn_cvt_pkrtz(c1B[4], c1B[5]));
                aB.w[3] = __builtin_bit_cast(int, __builtin_amdgcn_cvt_pkrtz(c1B[6], c1B[7]));
                #pragma unroll
                for (int m = 0; m < 8; ++m) {
                    aA.v[m] = (aA.v[m] > (f16)0.f) ? aA.v[m] : (f16)0.f;
                    aB.v[m] = (aB.v[m] > (f16)0.f) ? aB.v[m] : (f16)0.f;
                }
                aA.v[7] = hi ? (f16)1.f : aA.v[7];   // k2=15 bias slot
                aB.v[7] = hi ? (f16)1.f : aB.v[7];

                f32x16 c2A = __builtin_amdgcn_mfma_f32_32x32x16_f16(bf2p, aA.v, cz, 0, 0, 0);
                f32x16 c2B = __builtin_amdgcn_mfma_f32_32x32x16_f16(bf2p, aB.v, cz, 0, 0, 0);

                if (tb < 3) {
                    a0 += fmaxf(c2A[0], 0.f);  a1 += fmaxf(c2A[1], 0.f);
                    a2r += fmaxf(c2A[2], 0.f); a3 += fmaxf(c2A[3], 0.f);
                    b0 += fmaxf(c2B[0], 0.f);  b1 += fmaxf(c2B[1], 0.f);
                    b2r += fmaxf(c2B[2], 0.f); b3 += fmaxf(c2B[3], 0.f);
                } else {
                    a0 = fmaf(gtail, fmaxf(c2A[0], 0.f), a0);
                    a1 = fmaf(gtail, fmaxf(c2A[1], 0.f), a1);
                    a2r = fmaf(gtail, fmaxf(c2A[2], 0.f), a2r);
                    a3 = fmaf(gtail, fmaxf(c2A[3], 0.f), a3);
                    b0 = fmaf(gtail, fmaxf(c2B[0], 0.f), b0);
                    b1 = fmaf(gtail, fmaxf(c2B[1], 0.f), b1);
                    b2r = fmaf(gtail, fmaxf(c2B[2], 0.f), b2r);
                    b3 = fmaf(gtail, fmaxf(c2B[3], 0.f), b3);
                }
                jA += 32; if (jA >= 100) jA -= 100;
                jB += 32; if (jB >= 100) jB -= 100;
            }
            #pragma unroll
            for (int mk = 1; mk <= 16; mk <<= 1) {
                a0 += __shfl_xor(a0, mk);  a1 += __shfl_xor(a1, mk);
                a2r += __shfl_xor(a2r, mk); a3 += __shfl_xor(a3, mk);
                b0 += __shfl_xor(b0, mk);  b1 += __shfl_xor(b1, mk);
                b2r += __shfl_xor(b2r, mk); b3 += __shfl_xor(b3, mk);
            }
            if (l == 0) {
                float4 v; v.x = a0; v.y = a1; v.z = a2r; v.w = a3;
                *(float4*)&aggF[iA * 8] = v;
                float4 w; w.x = b0; w.y = b1; w.z = b2r; w.w = b3;
                *(float4*)&aggF[iB * 8] = w;
            } else if (l == 32) {
                float2 v; v.x = a0; v.y = a1;
                *(float2*)&aggF[iA * 8 + 4] = v;
                float2 w; w.x = b0; w.y = b1;
                *(float2*)&aggF[iB * 8 + 4] = w;
            }
        }
    }
    __syncthreads();

    // ---- fo MLP: per-node register chain, 8 waves x 13 lanes ----
    {
        const int wvF = tid >> 6;
        const int lF  = tid & 63;
        const int n   = wvF * 13 + lF;
        if (lF < 13 && n < NCONST) {
            float in[22];
            {
                const float4* xv = (const float4*)(&xbn[n][0]);
                float4 q0 = xv[0], q1 = xv[1], q2 = xv[2], q3 = xv[3];
                in[0]=q0.x;  in[1]=q0.y;  in[2]=q0.z;  in[3]=q0.w;
                in[4]=q1.x;  in[5]=q1.y;  in[6]=q1.z;  in[7]=q1.w;
                in[8]=q2.x;  in[9]=q2.y;  in[10]=q2.z; in[11]=q2.w;
                in[12]=q3.x; in[13]=q3.y; in[14]=q3.z; in[15]=q3.w;
                const float4 g0 = *(const float4*)(&aggF[n * 8]);
                const float2 g1 = *(const float2*)(&aggF[n * 8 + 4]);
                in[16]=g0.x; in[17]=g0.y; in[18]=g0.z; in[19]=g0.w;
                in[20]=g1.x; in[21]=g1.y;
            }
            float h1[45];
            #pragma unroll
            for (int o = 0; o < 45; ++o) h1[o] = fob1[o];
            #pragma unroll
            for (int k = 0; k < 22; ++k) {
                float v = in[k];
                #pragma unroll
                for (int o = 0; o < 45; ++o) h1[o] = fmaf(v, fow1[k * 45 + o], h1[o]);
            }
            #pragma unroll
            for (int o = 0; o < 45; ++o) h1[o] = fmaxf(h1[o], 0.f);

            float h2[22];
            #pragma unroll
            for (int o = 0; o < 22; ++o) h2[o] = fob2[o];
            #pragma unroll
            for (int k = 0; k < 45; ++k) {
                float v = h1[k];
                #pragma unroll
                for (int o = 0; o < 22; ++o) h2[o] = fmaf(v, fow2[k * 22 + o], h2[o]);
            }
            #pragma unroll
            for (int o = 0; o < 22; ++o) h2[o] = fmaxf(h2[o], 0.f);

            #pragma unroll
            for (int c = 0; c < 6; ++c) {
                float acc = fob3[c];
                #pragma unroll
                for (int k = 0; k < 22; ++k) acc = fmaf(h2[k], fow3[k * 6 + c], acc);
                atomicAdd(&fcin[c], fmaxf(acc, 0.f));
            }
        }
    }
    __syncthreads();

    // ---- fc: 6 -> 48 (relu) -> 5 -> softmax ----
    if (tid < 48) {
        float acc = fcb1[tid];
        #pragma unroll
        for (int k = 0; k < 6; ++k) acc = fmaf(fcin[k], fcw1[k * 48 + tid], acc);
        hfc[tid] = fmaxf(acc, 0.f);
    }
    __syncthreads();
    if (tid < 5) {
        float acc = fcb2[tid];
        #pragma unroll
        for (int k = 0; k < 48; ++k) acc = fmaf(hfc[k], fcw2[k * 5 + tid], acc);
        logits[tid] = acc;
    }
    __syncthreads();
    if (tid == 0) {
        float m = logits[0];
        #pragma unroll
        for (int c = 1; c < 5; ++c) m = fmaxf(m, logits[c]);
        float ex[5], sum = 0.f;
        #pragma unroll
        for (int c = 0; c < 5; ++c) { ex[c] = __expf(logits[c] - m); sum += ex[c]; }
        float inv = 1.f / sum;
        #pragma unroll
        for (int c = 0; c < 5; ++c) out[(size_t)b * 5 + c] = ex[c] * inv;
    }
}

extern "C" void kernel_launch(void* const* d_in, const int* in_sizes, int n_in,
                              void* d_out, int out_size, void* d_ws, size_t ws_size,
                              hipStream_t stream) {
    const float* x     = (const float*)d_in[0];
    const float* bn_g  = (const float*)d_in[1];
    const float* bn_b  = (const float*)d_in[2];
    const float* bn_m  = (const float*)d_in[3];
    const float* bn_v  = (const float*)d_in[4];
    const float* frw1  = (const float*)d_in[5];
    const float* frb1  = (const float*)d_in[6];
    const float* frw2  = (const float*)d_in[7];
    const float* frb2  = (const float*)d_in[8];
    const float* frw3  = (const float*)d_in[9];
    const float* frb3  = (const float*)d_in[10];
    const float* fow1  = (const float*)d_in[11];
    const float* fob1  = (const float*)d_in[12];
    const float* fow2  = (const float*)d_in[13];
    const float* fob2  = (const float*)d_in[14];
    const float* fow3  = (const float*)d_in[15];
    const float* fob3  = (const float*)d_in[16];
    const float* fcw1  = (const float*)d_in[17];
    const float* fcb1  = (const float*)d_in[18];
    const float* fcw2  = (const float*)d_in[19];
    const float* fcb2  = (const float*)d_in[20];

    const int B = in_sizes[0] / (NCONST * NF);   // 512

    convint_fused<<<dim3(B), dim3(BLK), 0, stream>>>(
        x, bn_g, bn_b, bn_m, bn_v,
        frw1, frb1, frw2, frb2, frw3, frb3,
        fow1, fob1, fow2, fob2, fow3, fob3,
        fcw1, fcb1, fcw2, fcb2,
        (float*)d_out);
}

// Round 19
// 61.060 us; speedup vs baseline: 1.3106x; 1.0489x over previous
//
#include <hip/hip_runtime.h>
#include <math.h>

#define NCONST 100
#define NF     16
#define BLK    512

typedef _Float16 f16;
typedef _Float16 f16x8 __attribute__((ext_vector_type(8)));
typedef _Float16 f16x4 __attribute__((ext_vector_type(4)));
typedef float    f32x16 __attribute__((ext_vector_type(16)));

// R15 exact restore -- best measured config (61.1 us headline / 62.7 per-dispatch).
// One block per batch element, 512 threads (8 waves), ~26 KB LDS.
// Edge: ILP-2 receivers, perm'd-W2 (D1 regs ARE the MFMA2 A-frag), C-chained
// MFMA1 pair (R17: splitting costs more VALU than it saves), transposed MFMA2,
// b2 folded k=30 / b3 folded k2=15, butterfly sum, plain stores.
// fo: per-node register chain, 4 waves x 25 lanes (R18: 8x13 doubles fo issue
// count -> regression; wave-instruction count is this kernel's currency).
// Lessons ledger: occupancy falsified 3x (R8/R10/R16); edge VALU-issue floor
// ~28us (R14 amplification probe); no pipe >40% busy -> latency/issue floor.
__global__ __launch_bounds__(BLK, 4) void convint_fused(
    const float* __restrict__ x,
    const float* __restrict__ bn_g, const float* __restrict__ bn_b,
    const float* __restrict__ bn_m, const float* __restrict__ bn_v,
    const float* __restrict__ frw1, const float* __restrict__ frb1,
    const float* __restrict__ frw2, const float* __restrict__ frb2,
    const float* __restrict__ frw3, const float* __restrict__ frb3,
    const float* __restrict__ fow1, const float* __restrict__ fob1,
    const float* __restrict__ fow2, const float* __restrict__ fob2,
    const float* __restrict__ fow3, const float* __restrict__ fob3,
    const float* __restrict__ fcw1, const float* __restrict__ fcb1,
    const float* __restrict__ fcw2, const float* __restrict__ fcb2,
    float* __restrict__ out)
{
    __shared__ float xbn[NCONST][NF];    // 6.4 KB
    __shared__ float upool[4000];        // 16 KB: Pr/Ps f16 (edge phase only)
    __shared__ float aggF[NCONST * 8];   // 3.2 KB
    __shared__ float fcin[8];
    __shared__ float hfc[48];
    __shared__ float logits[8];

    char* const PrB = (char*)upool;      // 8000 B, swizzled 16B slots
    char* const PsB = PrB + 8000;        // 8000 B

    const int b   = blockIdx.x;
    const int tid = threadIdx.x;
    const float* xb = x + (size_t)b * (NCONST * NF);

    for (int idx = tid; idx < NCONST * NF; idx += BLK) {
        int f = idx & 15;
        float sc = rsqrtf(bn_v[f] + 1e-3f) * bn_g[f];
        xbn[idx >> 4][f] = (xb[idx] - bn_m[f]) * sc + bn_b[f];
    }
    if (tid < 8) fcin[tid] = 0.f;
    __syncthreads();

    // ---- proj (R9-verified): Pr/Ps f16 rows of 40 halves, swizzled ----
    for (int idx = tid; idx < 1600; idx += BLK) {
        int n   = idx >> 4;
        int rem = idx & 15;
        int sel = rem >> 3;
        int oq  = rem & 7;
        int o0  = oq * 4;
        float xs[16];
        {
            const float4* xv = (const float4*)(&xbn[n][0]);
            float4 x0 = xv[0], x1 = xv[1], x2 = xv[2], x3 = xv[3];
            xs[0]=x0.x; xs[1]=x0.y; xs[2]=x0.z; xs[3]=x0.w;
            xs[4]=x1.x; xs[5]=x1.y; xs[6]=x1.z; xs[7]=x1.w;
            xs[8]=x2.x; xs[9]=x2.y; xs[10]=x2.z; xs[11]=x2.w;
            xs[12]=x3.x; xs[13]=x3.y; xs[14]=x3.z; xs[15]=x3.w;
        }
        float acc0 = (!sel) ? frb1[o0 + 0] : 0.f;
        float acc1 = (!sel) ? frb1[o0 + 1] : 0.f;
        float acc2 = (!sel && oq < 7) ? frb1[o0 + 2] : 0.f;
        float acc3 = (!sel && oq < 7) ? frb1[o0 + 3] : 0.f;
        const float* wbase = frw1 + sel * 16 * 30;
        const int wcol2 = (oq < 7) ? o0 + 2 : 28;
        #pragma unroll
        for (int f = 0; f < 16; ++f) {
            const float* wr = wbase + f * 30;
            float2 wa = *(const float2*)(wr + o0);
            float2 wb = *(const float2*)(wr + wcol2);
            acc0 = fmaf(xs[f], wa.x, acc0);
            acc1 = fmaf(xs[f], wa.y, acc1);
            acc2 = fmaf(xs[f], wb.x, acc2);
            acc3 = fmaf(xs[f], wb.y, acc3);
        }
        f16x4 hv;
        hv[0] = (f16)acc0;
        hv[1] = (f16)acc1;
        hv[2] = (oq < 7) ? (f16)acc2 : (sel ? (f16)0.f : (f16)1.f);  // half30: bias carrier
        hv[3] = (oq < 7) ? (f16)acc3 : (f16)0.f;                     // half31: 0 (k-pad)
        int slot = oq >> 1;
        int sw = (slot & 2) | ((slot ^ (n >> 3)) & 1);
        *(f16x4*)((sel ? PsB : PrB) + n * 80 + sw * 16 + (oq & 1) * 8) = hv;
    }
    __syncthreads();

    // ---- edge phase (R13/R15-verified core, ILP-2, C-chained MFMA1) ----
    {
        const int l  = tid & 63;
        const int wv = tid >> 6;
        const int e  = l & 31;
        const int hi = l >> 5;

        const int o2p = (e >= 4 && e < 12) ? (e ^ 12) : e;
        const bool o2v = (o2p < 15);
        const int  o2c = o2v ? o2p : 0;
        const bool o3v = (e < 6);
        const int  o3c = o3v ? e : 0;

        f16x8 bf1a, bf1b, bf2p;
        #pragma unroll
        for (int m = 0; m < 8; ++m) {
            int ka  = hi * 8 + m;
            int kb_ = 16 + ka;
            bf1a[m] = o2v ? (f16)frw2[ka * 15 + o2c] : (f16)0.f;
            f16 wb = (f16)0.f;
            if (o2v) {
                if (kb_ < 30)       wb = (f16)frw2[kb_ * 15 + o2c];
                else if (kb_ == 30) wb = (f16)frb2[o2c];
            }
            bf1b[m] = wb;
            f16 w3 = (f16)0.f;
            if (o3v) {
                if (ka < 15)       w3 = (f16)frw3[ka * 6 + o3c];
                else               w3 = (f16)frb3[o3c];
            }
            bf2p[m] = w3;
        }
        f32x16 cz;
        #pragma unroll
        for (int r = 0; r < 16; ++r) cz[r] = 0.f;
        const float gtail = (e < 3) ? 1.f : 0.f;

        for (int base = wv; base < 50; base += 8) {
            const int iA = base, iB = base + 50;
            const char* prpA = PrB + iA * 80 + ((hi ^ ((iA >> 3) & 1)) * 16);
            const char* prpB = PrB + iB * 80 + ((hi ^ ((iB >> 3) & 1)) * 16);
            f16x8 praA = *(const f16x8*)prpA;
            f16x8 prbA = *(const f16x8*)(prpA + 32);
            f16x8 praB = *(const f16x8*)prpB;
            f16x8 prbB = *(const f16x8*)(prpB + 32);
            float a0 = 0.f, a1 = 0.f, a2r = 0.f, a3 = 0.f;
            float b0 = 0.f, b1 = 0.f, b2r = 0.f, b3 = 0.f;

            int jA = iA + 1 + e; if (jA >= 100) jA -= 100;
            int jB = iB + 1 + e; if (jB >= 100) jB -= 100;
            #pragma unroll
            for (int tb = 0; tb < 4; ++tb) {
                const char* pspA = PsB + jA * 80 + ((hi ^ ((jA >> 3) & 1)) * 16);
                const char* pspB = PsB + jB * 80 + ((hi ^ ((jB >> 3) & 1)) * 16);
                f16x8 psaA = *(const f16x8*)pspA;
                f16x8 psbA = *(const f16x8*)(pspA + 32);
                f16x8 psaB = *(const f16x8*)pspB;
                f16x8 psbB = *(const f16x8*)(pspB + 32);

                f16x8 h1aA = praA + psaA, h1bA = prbA + psbA;
                f16x8 h1aB = praB + psaB, h1bB = prbB + psbB;
                #pragma unroll
                for (int m = 0; m < 8; ++m) {
                    h1aA[m] = (h1aA[m] > (f16)0.f) ? h1aA[m] : (f16)0.f;
                    h1bA[m] = (h1bA[m] > (f16)0.f) ? h1bA[m] : (f16)0.f;
                    h1aB[m] = (h1aB[m] > (f16)0.f) ? h1aB[m] : (f16)0.f;
                    h1bB[m] = (h1bB[m] > (f16)0.f) ? h1bB[m] : (f16)0.f;
                }
                f32x16 c1A = __builtin_amdgcn_mfma_f32_32x32x16_f16(bf1a, h1aA, cz, 0, 0, 0);
                f32x16 c1B = __builtin_amdgcn_mfma_f32_32x32x16_f16(bf1a, h1aB, cz, 0, 0, 0);
                c1A = __builtin_amdgcn_mfma_f32_32x32x16_f16(bf1b, h1bA, c1A, 0, 0, 0);
                c1B = __builtin_amdgcn_mfma_f32_32x32x16_f16(bf1b, h1bB, c1B, 0, 0, 0);

                union { int w[4]; f16x8 v; } aA, aB;
                aA.w[0] = __builtin_bit_cast(int, __builtin_amdgcn_cvt_pkrtz(c1A[0], c1A[1]));
                aA.w[1] = __builtin_bit_cast(int, __builtin_amdgcn_cvt_pkrtz(c1A[2], c1A[3]));
                aA.w[2] = __builtin_bit_cast(int, __builtin_amdgcn_cvt_pkrtz(c1A[4], c1A[5]));
                aA.w[3] = __builtin_bit_cast(int, __builtin_amdgcn_cvt_pkrtz(c1A[6], c1A[7]));
                aB.w[0] = __builtin_bit_cast(int, __builtin_amdgcn_cvt_pkrtz(c1B[0], c1B[1]));
                aB.w[1] = __builtin_bit_cast(int, __builtin_amdgcn_cvt_pkrtz(c1B[2], c1B[3]));
                aB.w[2] = __builtin_bit_cast(int, __builtin_amdgcn_cvt_pkrtz(c1B[4], c1B[5]));
                aB.w[3] = __builtin_bit_cast(int, __builtin_amdgcn_cvt_pkrtz(c1B[6], c1B[7]));
                #pragma unroll
                for (int m = 0; m < 8; ++m) {
                    aA.v[m] = (aA.v[m] > (f16)0.f) ? aA.v[m] : (f16)0.f;
                    aB.v[m] = (aB.v[m] > (f16)0.f) ? aB.v[m] : (f16)0.f;
                }
                aA.v[7] = hi ? (f16)1.f : aA.v[7];   // k2=15 bias slot
                aB.v[7] = hi ? (f16)1.f : aB.v[7];

                f32x16 c2A = __builtin_amdgcn_mfma_f32_32x32x16_f16(bf2p, aA.v, cz, 0, 0, 0);
                f32x16 c2B = __builtin_amdgcn_mfma_f32_32x32x16_f16(bf2p, aB.v, cz, 0, 0, 0);

                if (tb < 3) {
                    a0 += fmaxf(c2A[0], 0.f);  a1 += fmaxf(c2A[1], 0.f);
                    a2r += fmaxf(c2A[2], 0.f); a3 += fmaxf(c2A[3], 0.f);
                    b0 += fmaxf(c2B[0], 0.f);  b1 += fmaxf(c2B[1], 0.f);
                    b2r += fmaxf(c2B[2], 0.f); b3 += fmaxf(c2B[3], 0.f);
                } else {
                    a0 = fmaf(gtail, fmaxf(c2A[0], 0.f), a0);
                    a1 = fmaf(gtail, fmaxf(c2A[1], 0.f), a1);
                    a2r = fmaf(gtail, fmaxf(c2A[2], 0.f), a2r);
                    a3 = fmaf(gtail, fmaxf(c2A[3], 0.f), a3);
                    b0 = fmaf(gtail, fmaxf(c2B[0], 0.f), b0);
                    b1 = fmaf(gtail, fmaxf(c2B[1], 0.f), b1);
                    b2r = fmaf(gtail, fmaxf(c2B[2], 0.f), b2r);
                    b3 = fmaf(gtail, fmaxf(c2B[3], 0.f), b3);
                }
                jA += 32; if (jA >= 100) jA -= 100;
                jB += 32; if (jB >= 100) jB -= 100;
            }
            #pragma unroll
            for (int mk = 1; mk <= 16; mk <<= 1) {
                a0 += __shfl_xor(a0, mk);  a1 += __shfl_xor(a1, mk);
                a2r += __shfl_xor(a2r, mk); a3 += __shfl_xor(a3, mk);
                b0 += __shfl_xor(b0, mk);  b1 += __shfl_xor(b1, mk);
                b2r += __shfl_xor(b2r, mk); b3 += __shfl_xor(b3, mk);
            }
            if (l == 0) {
                float4 v; v.x = a0; v.y = a1; v.z = a2r; v.w = a3;
                *(float4*)&aggF[iA * 8] = v;
                float4 w; w.x = b0; w.y = b1; w.z = b2r; w.w = b3;
                *(float4*)&aggF[iB * 8] = w;
            } else if (l == 32) {
                float2 v; v.x = a0; v.y = a1;
                *(float2*)&aggF[iA * 8 + 4] = v;
                float2 w; w.x = b0; w.y = b1;
                *(float2*)&aggF[iB * 8 + 4] = w;
            }
        }
    }
    __syncthreads();

    // ---- fo MLP: per-node register chain, 4 waves x 25 lanes (R15) ----
    {
        const int wvF = tid >> 6;
        const int lF  = tid & 63;
        if (wvF < 4 && lF < 25) {
            const int n = wvF * 25 + lF;
            float in[22];
            {
                const float4* xv = (const float4*)(&xbn[n][0]);
                float4 q0 = xv[0], q1 = xv[1], q2 = xv[2], q3 = xv[3];
                in[0]=q0.x;  in[1]=q0.y;  in[2]=q0.z;  in[3]=q0.w;
                in[4]=q1.x;  in[5]=q1.y;  in[6]=q1.z;  in[7]=q1.w;
                in[8]=q2.x;  in[9]=q2.y;  in[10]=q2.z; in[11]=q2.w;
                in[12]=q3.x; in[13]=q3.y; in[14]=q3.z; in[15]=q3.w;
                const float4 g0 = *(const float4*)(&aggF[n * 8]);
                const float2 g1 = *(const float2*)(&aggF[n * 8 + 4]);
                in[16]=g0.x; in[17]=g0.y; in[18]=g0.z; in[19]=g0.w;
                in[20]=g1.x; in[21]=g1.y;
            }
            float h1[45];
            #pragma unroll
            for (int o = 0; o < 45; ++o) h1[o] = fob1[o];
            #pragma unroll
            for (int k = 0; k < 22; ++k) {
                float v = in[k];
                #pragma unroll
                for (int o = 0; o < 45; ++o) h1[o] = fmaf(v, fow1[k * 45 + o], h1[o]);
            }
            #pragma unroll
            for (int o = 0; o < 45; ++o) h1[o] = fmaxf(h1[o], 0.f);

            float h2[22];
            #pragma unroll
            for (int o = 0; o < 22; ++o) h2[o] = fob2[o];
            #pragma unroll
            for (int k = 0; k < 45; ++k) {
                float v = h1[k];
                #pragma unroll
                for (int o = 0; o < 22; ++o) h2[o] = fmaf(v, fow2[k * 22 + o], h2[o]);
            }
            #pragma unroll
            for (int o = 0; o < 22; ++o) h2[o] = fmaxf(h2[o], 0.f);

            #pragma unroll
            for (int c = 0; c < 6; ++c) {
                float acc = fob3[c];
                #pragma unroll
                for (int k = 0; k < 22; ++k) acc = fmaf(h2[k], fow3[k * 6 + c], acc);
                atomicAdd(&fcin[c], fmaxf(acc, 0.f));
            }
        }
    }
    __syncthreads();

    // ---- fc: 6 -> 48 (relu) -> 5 -> softmax ----
    if (tid < 48) {
        float acc = fcb1[tid];
        #pragma unroll
        for (int k = 0; k < 6; ++k) acc = fmaf(fcin[k], fcw1[k * 48 + tid], acc);
        hfc[tid] = fmaxf(acc, 0.f);
    }
    __syncthreads();
    if (tid < 5) {
        float acc = fcb2[tid];
        #pragma unroll
        for (int k = 0; k < 48; ++k) acc = fmaf(hfc[k], fcw2[k * 5 + tid], acc);
        logits[tid] = acc;
    }
    __syncthreads();
    if (tid == 0) {
        float m = logits[0];
        #pragma unroll
        for (int c = 1; c < 5; ++c) m = fmaxf(m, logits[c]);
        float ex[5], sum = 0.f;
        #pragma unroll
        for (int c = 0; c < 5; ++c) { ex[c] = __expf(logits[c] - m); sum += ex[c]; }
        float inv = 1.f / sum;
        #pragma unroll
        for (int c = 0; c < 5; ++c) out[(size_t)b * 5 + c] = ex[c] * inv;
    }
}

extern "C" void kernel_launch(void* const* d_in, const int* in_sizes, int n_in,
                              void* d_out, int out_size, void* d_ws, size_t ws_size,
                              hipStream_t stream) {
    const float* x     = (const float*)d_in[0];
    const float* bn_g  = (const float*)d_in[1];
    const float* bn_b  = (const float*)d_in[2];
    const float* bn_m  = (const float*)d_in[3];
    const float* bn_v  = (const float*)d_in[4];
    const float* frw1  = (const float*)d_in[5];
    const float* frb1  = (const float*)d_in[6];
    const float* frw2  = (const float*)d_in[7];
    const float* frb2  = (const float*)d_in[8];
    const float* frw3  = (const float*)d_in[9];
    const float* frb3  = (const float*)d_in[10];
    const float* fow1  = (const float*)d_in[11];
    const float* fob1  = (const float*)d_in[12];
    const float* fow2  = (const float*)d_in[13];
    const float* fob2  = (const float*)d_in[14];
    const float* fow3  = (const float*)d_in[15];
    const float* fob3  = (const float*)d_in[16];
    const float* fcw1  = (const float*)d_in[17];
    const float* fcb1  = (const float*)d_in[18];
    const float* fcw2  = (const float*)d_in[19];
    const float* fcb2  = (const float*)d_in[20];

    const int B = in_sizes[0] / (NCONST * NF);   // 512

    convint_fused<<<dim3(B), dim3(BLK), 0, stream>>>(
        x, bn_g, bn_b, bn_m, bn_v,
        frw1, frb1, frw2, frb2, frw3, frb3,
        fow1, fob1, fow2, fob2, fow3, fob3,
        fcw1, fcb1, fcw2, fcb2,
        (float*)d_out);
}